// Round 7
// baseline (762.176 us; speedup 1.0000x reference)
//
#include <hip/hip_runtime.h>

namespace {
constexpr int NZ = 256, NX = 256, NT = 256, NR = 128, B = 4;
constexpr int K = 8;                     // steps per sync round
constexpr int OROWS = 4;                 // rows owned per block
constexpr int IROWS = OROWS + 2 * K;     // 20-row window (K-step cone)
constexpr int NSTRIP = 4;                // z-strips per block
constexpr int RPT = IROWS / NSTRIP;      // 5 rows per thread
constexpr int ZB = NZ / OROWS;           // 64 z-blocks per shot
constexpr int NBLK = B * ZB;             // 256 blocks (1 per CU)
constexpr int NL = NT / K;               // 32 rounds
constexpr float DT = 1e-3f, DH = 10.0f, OMEGA = 10.0f;
constexpr float TS  = 1.0f / OMEGA;
constexpr float CBv = 1.0f + DT / (2.0f * TS);
constexpr float CA  = (1.0f - DT / (2.0f * TS)) / CBv;

// lane i <- lane i-1 (wave_shr:1); lane 0 <- 0
__device__ inline float dpp_shr1(float v) {
  int r = __builtin_amdgcn_update_dpp(0, __builtin_bit_cast(int, v),
                                      0x138, 0xF, 0xF, false);
  return __builtin_bit_cast(float, r);
}
// lane i <- lane i+1 (wave_shl:1); lane 63 <- 0
__device__ inline float dpp_shl1(float v) {
  int r = __builtin_amdgcn_update_dpp(0, __builtin_bit_cast(int, v),
                                      0x130, 0xF, 0xF, false);
  return __builtin_bit_cast(float, r);
}
}

// Persistent time-skewed solver. Block = 4 z-strips x 256 cols, owns window
// rows [K, K+OROWS) for the whole run (state + coefs in registers). Per round:
// wait neighbor flags >= r, reload 16 halo rows from pub[r&1] (plain cached
// loads; tid-0's acquire invalidated this CU's L1/L2), run K substeps
// (arithmetic identical to the verified round-6 kernel), publish owned rows
// to pub[(r+1)&1], release flag = r+1.
// WAR proof: I overwrite pub[(r+1)&1] (round r-1 data) only during round r,
// which I entered after flags[zb+/-1,2] >= r, i.e. after every possible
// reader finished its round r-1 reads of that buffer.
__global__ __launch_bounds__(1024, 4) void wave_persist(
    const float* __restrict__ vp, const float* __restrict__ rho,
    const float* __restrict__ Q, const float* __restrict__ wav,
    const int* __restrict__ src_z, const int* __restrict__ src_x,
    const int* __restrict__ rec_x, const int* __restrict__ rec_z,
    float* __restrict__ out,
    float4* __restrict__ pub,            // [2][B][NZ][NX]
    int* __restrict__ flags)             // [NBLK], zeroed per call
{
  const int tid  = threadIdx.x;
  const int x    = tid & (NX - 1);       // column 0..255
  const int g    = tid >> 8;             // strip 0..3
  const int lane = x & 63;
  const int wx   = x >> 6;               // wave-in-strip 0..3
  const int j0   = g * RPT;
  const int bid  = blockIdx.x;
  const int b    = bid / ZB, zb = bid % ZB;
  const int z0   = zb * OROWS;
  const int zi0  = z0 - K;
  const size_t base = (size_t)b * NZ * NX;

  __shared__ float pse[NSTRIP][NX];      // strip bottom-row p
  __shared__ float vze[NSTRIP][NX];      // strip top-row vz
  __shared__ float pxe[NSTRIP][4][RPT];  // lane-63 p of each wave
  __shared__ float vxe_s[NSTRIP][4][RPT];// lane-0 vx of each wave
  __shared__ float prow[NX];             // receiver row staging
  __shared__ float wav_s[NT];
  __shared__ int   rx_s[NR];

  float pr[RPT], vxr[RPT], vz[RPT], rr[RPT], a1[RPT], b2[RPT], b3[RPT];

  // ---- one-time init: coefficients (registers, kept all run), wavelet ----
  #pragma unroll
  for (int jj = 0; jj < RPT; ++jj) {
    int gz = zi0 + j0 + jj;
    bool in = (unsigned)gz < (unsigned)NZ;
    size_t ci = (size_t)gz * NX + x;
    float rh = in ? rho[ci] : 1.0f;
    float v  = in ? vp[ci]  : 0.0f;
    float q  = in ? Q[ci]   : 1.0f;
    float kappa = rh * v * v, tau = 1.0f / q;
    a1[jj] = in ? DT / (rh * DH) : 0.0f;               // zero coef outside
    b2[jj] = in ? DT * kappa * tau / (TS * CBv * DH) : 0.0f;
    b3[jj] = in ? DT * kappa * (1.0f + tau) / DH : 0.0f;
    pr[jj] = vxr[jj] = vz[jj] = rr[jj] = 0.0f;
  }
  wav_s[tid & (NT - 1)] = wav[b * NT + (tid & (NT - 1))];
  if (tid < NR) rx_s[tid] = rec_x[tid];
  const int sz = src_z[b], sx = src_x[b];
  const int rz = rec_z[0];
  const bool owner = (rz >= z0 && rz < z0 + OROWS);    // unique block per shot
  const int jrow = rz - zi0;                           // in [K, K+OROWS)

  for (int r = 0; r < NL; ++r) {
    // ---- acquire neighbor flags, reload halo rows ----
    if (r > 0) {
      if (tid < 4) {
        int off = (tid < 2) ? tid - 2 : tid - 1;       // -2,-1,+1,+2
        int nzb = zb + off;
        if (nzb >= 0 && nzb < ZB) {
          int gd = 0;
          while (__hip_atomic_load(&flags[b * ZB + nzb], __ATOMIC_ACQUIRE,
                                   __HIP_MEMORY_SCOPE_AGENT) < r &&
                 ++gd < (1 << 27)) {}
        }
      }
      __syncthreads();                                 // order: flags -> loads
      const float4* src = pub + (size_t)(r & 1) * B * NZ * NX;
      #pragma unroll
      for (int jj = 0; jj < RPT; ++jj) {
        int j = j0 + jj;
        if (j >= K && j < K + OROWS) continue;         // owned rows persist
        int gz = zi0 + j;
        float4 st = make_float4(0, 0, 0, 0);
        if ((unsigned)gz < (unsigned)NZ)
          st = src[base + (size_t)gz * NX + x];
        pr[jj] = st.x; vxr[jj] = st.y; vz[jj] = st.z; rr[jj] = st.w;
      }
    }
    // ---- seam LDS init for this round ----
    pse[g][x] = pr[RPT - 1];
    if (wx < 3 && lane == 63) {
      #pragma unroll
      for (int jj = 0; jj < RPT; ++jj) pxe[g][wx][jj] = pr[jj];
    }
    __syncthreads();

    for (int s = 0; s < K; ++s) {
      // ---------- phase A: velocities ----------
      float pu0 = (g > 0) ? pse[g - 1][x] : 0.0f;
      float ple[RPT] = {0, 0, 0, 0, 0};
      if (wx > 0 && lane == 0) {
        #pragma unroll
        for (int jj = 0; jj < RPT; ++jj) ple[jj] = pxe[g][wx - 1][jj];
      }
      #pragma unroll
      for (int jj = 0; jj < RPT; ++jj) {
        float pc = pr[jj];
        float pl = dpp_shr1(pc);
        if (lane == 0) pl = ple[jj];
        float pu = jj ? pr[jj - 1] : pu0;
        vxr[jj] -= a1[jj] * (pc - pl);
        vz[jj]  -= a1[jj] * (pc - pu);
      }
      vze[g][x] = vz[0];
      if (wx > 0 && lane == 0) {
        #pragma unroll
        for (int jj = 0; jj < RPT; ++jj) vxe_s[g][wx][jj] = vxr[jj];
      }
      __syncthreads();

      // ---------- phase B: div, memory var, pressure ----------
      float vzb_ = (g < NSTRIP - 1) ? vze[g + 1][x] : 0.0f;
      float vxe[RPT] = {0, 0, 0, 0, 0};
      if (wx < 3 && lane == 63) {
        #pragma unroll
        for (int jj = 0; jj < RPT; ++jj) vxe[jj] = vxe_s[g][wx + 1][jj];
      }
      const float xi = wav_s[r * K + s];
      #pragma unroll
      for (int jj = 0; jj < RPT; ++jj) {
        float vxR = dpp_shl1(vxr[jj]);
        if (lane == 63) vxR = vxe[jj];
        float vzn = (jj < RPT - 1) ? vz[jj + 1] : vzb_;
        float div = (vxR - vxr[jj]) + (vzn - vz[jj]);
        float rn = CA * rr[jj] - b2[jj] * div;
        rr[jj] = rn;
        float pn = pr[jj] - b3[jj] * div + DT * rn;
        if (zi0 + j0 + jj == sz && x == sx) pn += xi;
        pr[jj] = pn;
      }
      pse[g][x] = pr[RPT - 1];
      if (wx < 3 && lane == 63) {
        #pragma unroll
        for (int jj = 0; jj < RPT; ++jj) pxe[g][wx][jj] = pr[jj];
      }
      if (owner) {
        #pragma unroll
        for (int jj = 0; jj < RPT; ++jj)
          if (j0 + jj == jrow) prow[x] = pr[jj];
      }
      __syncthreads();
      if (owner && tid < NR)
        out[(size_t)(r * K + s) * NR * B + (size_t)tid * B + b] =
            prow[rx_s[tid]];
      // fast threads can't overwrite prow before this read: the next B-phase
      // prow write is behind the next A-phase barrier, which waits for us.
    }

    // ---- publish owned rows (time (r+1)*K) + release flag ----
    {
      float4* dst = pub + (size_t)((r + 1) & 1) * B * NZ * NX;
      #pragma unroll
      for (int jj = 0; jj < RPT; ++jj) {
        int j = j0 + jj;
        if (j >= K && j < K + OROWS)
          dst[base + (size_t)(zi0 + j) * NX + x] =
              make_float4(pr[jj], vxr[jj], vz[jj], rr[jj]);
      }
    }
    __syncthreads();   // each thread drains vmcnt before barrier -> all of the
                       // block's publish stores are in this XCD's L2
    if (tid == 0)      // release: writes back L2, then flag visible at LLC
      __hip_atomic_store(&flags[bid], r + 1, __ATOMIC_RELEASE,
                         __HIP_MEMORY_SCOPE_AGENT);
  }
}

extern "C" void kernel_launch(void* const* d_in, const int* in_sizes, int n_in,
                              void* d_out, int out_size, void* d_ws, size_t ws_size,
                              hipStream_t stream) {
  const float* xw  = (const float*)d_in[0];
  const float* vp  = (const float*)d_in[1];
  const float* rho = (const float*)d_in[2];
  const float* Q   = (const float*)d_in[3];
  const int* src_z = (const int*)d_in[4];
  const int* src_x = (const int*)d_in[5];
  const int* rec_x = (const int*)d_in[6];
  const int* rec_z = (const int*)d_in[7];
  float* out = (float*)d_out;

  float4* pub = (float4*)d_ws;                       // [2][B][NZ][NX] = 8 MB
  int* flags  = (int*)(pub + (size_t)2 * B * NZ * NX);

  hipMemsetAsync(flags, 0, NBLK * sizeof(int), stream);
  wave_persist<<<NBLK, 1024, 0, stream>>>(vp, rho, Q, xw, src_z, src_x,
                                          rec_x, rec_z, out, pub, flags);
}

// Round 8
// 370.551 us; speedup vs baseline: 2.0569x; 2.0569x over previous
//
#include <hip/hip_runtime.h>

namespace {
constexpr int NZ = 256, NX = 256, NT = 256, NR = 128, B = 4;
constexpr int K = 8;                     // fused time steps per launch
constexpr int OROWS = 4;                 // rows owned (written back) per block
constexpr int IROWS = OROWS + 2 * K;     // 20-row window (K-step cone)
constexpr int NSTRIP = 4;                // z-strips per block
constexpr int RPT = IROWS / NSTRIP;      // 5 rows per thread
constexpr int ZB = NZ / OROWS;           // 64 z-blocks per shot
constexpr int NBLK = B * ZB;             // 256 blocks
constexpr int NL = NT / K;               // 32 launches
constexpr int NXCD = 8;
constexpr int CHUNK = NBLK / NXCD;       // 32 logical blocks per XCD
constexpr float DT = 1e-3f, DH = 10.0f, OMEGA = 10.0f;
constexpr float TS  = 1.0f / OMEGA;
constexpr float CBv = 1.0f + DT / (2.0f * TS);
constexpr float CA  = (1.0f - DT / (2.0f * TS)) / CBv;

// lane i <- lane i-1 (wave_shr:1); lane 0 <- 0
__device__ inline float dpp_shr1(float v) {
  int r = __builtin_amdgcn_update_dpp(0, __builtin_bit_cast(int, v),
                                      0x138, 0xF, 0xF, false);
  return __builtin_bit_cast(float, r);
}
// lane i <- lane i+1 (wave_shl:1); lane 63 <- 0
__device__ inline float dpp_shl1(float v) {
  int r = __builtin_amdgcn_update_dpp(0, __builtin_bit_cast(int, v),
                                      0x130, 0xF, 0xF, false);
  return __builtin_bit_cast(float, r);
}
}

// cf = (a1, b2, b3, 0) = (DT/(rho DH), DT k tau/(TS cb DH), DT k (1+tau)/DH, 0)
__global__ void coef_kernel(const float* __restrict__ vp, const float* __restrict__ rho,
                            const float* __restrict__ Q, float4* __restrict__ cf) {
  int i = blockIdx.x * blockDim.x + threadIdx.x;
  if (i >= NZ * NX) return;
  float v = vp[i], rh = rho[i], q = Q[i];
  float kappa = rh * v * v, tau = 1.0f / q;
  cf[i] = make_float4(DT / (rh * DH), DT * kappa * tau / (TS * CBv * DH),
                      DT * kappa * (1.0f + tau) / DH, 0.0f);
}

// Time-skewed K-step block (arithmetic identical to the verified round-6
// kernel). 1024 threads = 4 z-strips x 256 cols; thread holds 5 rows of
// (p,vx,vz,r,a1,b2,b3) in registers. x-neighbors via DPP wave shifts; strip
// seams via small LDS buffers.
// NEW: XCD-chunked logical-block swizzle — hardware round-robins blockIdx
// across the 8 XCDs, so lbid = (bid%8)*32 + bid/8 gives each XCD a chunk of
// 32 CONTIGUOUS z-blocks. A block's window rows were then written (previous
// launch) by blocks on its own XCD -> halo/coef reads hit the local L2
// instead of crossing to LLC/HBM.
__global__ __launch_bounds__(1024, 4) void step_fused(
    const float4* __restrict__ Sin, float4* __restrict__ Sout,
    const float4* __restrict__ Cf, const float* __restrict__ wav,
    const int* __restrict__ src_z, const int* __restrict__ src_x,
    const int* __restrict__ rec_x, const int* __restrict__ rec_z,
    float* __restrict__ out, int t0)
{
  const int tid  = threadIdx.x;
  const int x    = tid & (NX - 1);       // column 0..255
  const int g    = tid >> 8;             // strip 0..3
  const int lane = x & 63;               // lane in wave
  const int wx   = x >> 6;               // wave-in-strip 0..3
  const int j0   = g * RPT;              // first window row of strip
  const int lbid = (blockIdx.x & (NXCD - 1)) * CHUNK + (blockIdx.x >> 3);
  const int b    = lbid / ZB, zb = lbid % ZB;
  const int z0   = zb * OROWS;
  const int zi0  = z0 - K;               // first loaded global row (may be <0)
  const size_t base = (size_t)b * NZ * NX;

  __shared__ float pse[NSTRIP][NX];      // strip bottom-row p  (row j0+RPT-1)
  __shared__ float vze[NSTRIP][NX];      // strip top-row vz    (row j0)
  __shared__ float pxe[NSTRIP][4][RPT];  // lane-63 p  of each wave (5 rows)
  __shared__ float vxe_s[NSTRIP][4][RPT];// lane-0  vx of each wave (5 rows)
  __shared__ float prow[NX];             // receiver row staging
  __shared__ float wav_s[K];
  __shared__ int   rx_s[NR];

  float pr[RPT], vxr[RPT], vz[RPT], rr[RPT], a1[RPT], b2[RPT], b3[RPT];

  // ---- load window (AoS float4); zero coefs outside domain = exact ghosts ----
  #pragma unroll
  for (int jj = 0; jj < RPT; ++jj) {
    int gz = zi0 + j0 + jj;
    bool in = (unsigned)gz < (unsigned)NZ;
    float4 st = in ? Sin[base + (size_t)gz * NX + x] : make_float4(0, 0, 0, 0);
    float4 cf = in ? Cf[(size_t)gz * NX + x]        : make_float4(0, 0, 0, 0);
    pr[jj] = st.x; vxr[jj] = st.y; vz[jj] = st.z; rr[jj] = st.w;
    a1[jj] = cf.x; b2[jj] = cf.y; b3[jj] = cf.z;
  }
  pse[g][x] = pr[RPT - 1];
  if (wx < 3 && lane == 63) {
    #pragma unroll
    for (int jj = 0; jj < RPT; ++jj) pxe[g][wx][jj] = pr[jj];
  }
  if (tid < NR) rx_s[tid] = rec_x[tid];
  if (tid < K)  wav_s[tid] = wav[b * NT + t0 + tid];
  const int sz = src_z[b], sx = src_x[b];
  const int rz = rec_z[0];
  const bool owner = (rz >= z0 && rz < z0 + OROWS);  // unique block per shot
  const int jrow = rz - zi0;                         // in [K, K+OROWS)
  __syncthreads();

  for (int s = 0; s < K; ++s) {
    // ---------- phase A: velocities ----------
    float pu0 = (g > 0) ? pse[g - 1][x] : 0.0f;      // row j0-1 p (old)
    float ple[RPT] = {0, 0, 0, 0, 0};
    if (wx > 0 && lane == 0) {                       // cross-wave p[x-1]
      #pragma unroll
      for (int jj = 0; jj < RPT; ++jj) ple[jj] = pxe[g][wx - 1][jj];
    }
    #pragma unroll
    for (int jj = 0; jj < RPT; ++jj) {
      float pc = pr[jj];
      float pl = dpp_shr1(pc);                       // p[x-1] in-wave
      if (lane == 0) pl = ple[jj];                   // x==0 -> 0 ghost
      float pu = jj ? pr[jj - 1] : pu0;              // p[j-1]
      vxr[jj] -= a1[jj] * (pc - pl);
      vz[jj]  -= a1[jj] * (pc - pu);
    }
    vze[g][x] = vz[0];                               // strip top vz for strip g-1
    if (wx > 0 && lane == 0) {                       // cross-wave vx[x+1] source
      #pragma unroll
      for (int jj = 0; jj < RPT; ++jj) vxe_s[g][wx][jj] = vxr[jj];
    }
    __syncthreads();

    // ---------- phase B: div, memory var, pressure ----------
    float vzb_ = (g < NSTRIP - 1) ? vze[g + 1][x] : 0.0f;  // row j0+RPT vz
    float vxe[RPT] = {0, 0, 0, 0, 0};
    if (wx < 3 && lane == 63) {
      #pragma unroll
      for (int jj = 0; jj < RPT; ++jj) vxe[jj] = vxe_s[g][wx + 1][jj];
    }
    const float xi = wav_s[s];
    #pragma unroll
    for (int jj = 0; jj < RPT; ++jj) {
      float vxR = dpp_shl1(vxr[jj]);                 // vx[x+1] in-wave
      if (lane == 63) vxR = vxe[jj];                 // x==255 -> 0 ghost
      float vzn = (jj < RPT - 1) ? vz[jj + 1] : vzb_;
      float div = (vxR - vxr[jj]) + (vzn - vz[jj]);
      float rn = CA * rr[jj] - b2[jj] * div;
      rr[jj] = rn;
      float pn = pr[jj] - b3[jj] * div + DT * rn;
      if (zi0 + j0 + jj == sz && x == sx) pn += xi;  // source injection
      pr[jj] = pn;
    }
    pse[g][x] = pr[RPT - 1];
    if (wx < 3 && lane == 63) {
      #pragma unroll
      for (int jj = 0; jj < RPT; ++jj) pxe[g][wx][jj] = pr[jj];
    }
    if (owner) {                                     // stage receiver row
      #pragma unroll
      for (int jj = 0; jj < RPT; ++jj)
        if (j0 + jj == jrow) prow[x] = pr[jj];
    }
    __syncthreads();
    // probe reads complete before any thread reaches next A->B barrier -> safe
    if (owner && tid < NR)
      out[(size_t)(t0 + s) * NR * B + (size_t)tid * B + b] = prow[rx_s[tid]];
  }

  // ---- store owned rows (valid after exactly K steps) ----
  #pragma unroll
  for (int jj = 0; jj < RPT; ++jj) {
    int j = j0 + jj;
    if (j >= K && j < K + OROWS)
      Sout[base + (size_t)(zi0 + j) * NX + x] =
          make_float4(pr[jj], vxr[jj], vz[jj], rr[jj]);
  }
}

extern "C" void kernel_launch(void* const* d_in, const int* in_sizes, int n_in,
                              void* d_out, int out_size, void* d_ws, size_t ws_size,
                              hipStream_t stream) {
  const float* xw  = (const float*)d_in[0];
  const float* vp  = (const float*)d_in[1];
  const float* rho = (const float*)d_in[2];
  const float* Q   = (const float*)d_in[3];
  const int* src_z = (const int*)d_in[4];
  const int* src_x = (const int*)d_in[5];
  const int* rec_x = (const int*)d_in[6];
  const int* rec_z = (const int*)d_in[7];
  float* out = (float*)d_out;

  const size_t S = (size_t)B * NZ * NX;          // cells per state buffer
  float4* s0 = (float4*)d_ws;                    // state ping  [S] float4
  float4* s1 = s0 + S;                           // state pong  [S] float4
  float4* cf = s1 + S;                           // coefs       [NZ*NX] float4

  hipMemsetAsync(s0, 0, S * sizeof(float4), stream);   // zero initial state
  coef_kernel<<<(NZ * NX + 255) / 256, 256, 0, stream>>>(vp, rho, Q, cf);

  for (int l = 0; l < NL; ++l) {
    float4* in   = (l & 1) ? s1 : s0;
    float4* out4 = (l & 1) ? s0 : s1;
    step_fused<<<NBLK, 1024, 0, stream>>>(in, out4, cf, xw, src_z, src_x,
                                          rec_x, rec_z, out, l * K);
  }
}